// Round 4
// baseline (1246.681 us; speedup 1.0000x reference)
//
#include <hip/hip_runtime.h>
#include <stdint.h>

#define DD 96
#define VV (96*96*96)   // 884736
#define PR 9604         // 98*98 padded (z,y) rows per batch
#define ROWE 3072       // 96 x * 32 c elements per row
#define EPSN 1e-5f

typedef short short8 __attribute__((ext_vector_type(8)));
typedef float floatx4 __attribute__((ext_vector_type(4)));

__device__ __forceinline__ float bf2f(uint32_t u_lo16) {
    union { uint32_t i; float f; } x; x.i = u_lo16 << 16; return x.f;
}
__device__ __forceinline__ uint16_t f2bf(float f) {
    union { float f; uint32_t i; } x; x.f = f;
    uint32_t r = x.i + 0x7FFFu + ((x.i >> 16) & 1u);
    return (uint16_t)(r >> 16);
}
__device__ __forceinline__ uint32_t cvtpk(float lo, float hi) {
    uint32_t r;
    asm("v_cvt_pk_bf16_f32 %0, %1, %2" : "=v"(r) : "v"(lo), "v"(hi));
    return r;
}

// ---------------- weight packing ----------------
__global__ void k_packw(const float* __restrict__ w0, const float* __restrict__ wk,
                        float* __restrict__ wT0, uint16_t* __restrict__ wpk) {
    int i = blockIdx.x * 256 + threadIdx.x;
    if (i < 27 * 32) {
        int co = i / 27, k = i % 27;
        wT0[k * 32 + co] = w0[i];
    }
    int j = i - 27 * 32;
    if (j >= 0 && j < 3 * 27 * 2 * 512) {
        int e = j & 7, l = (j >> 3) & 63, nt = (j >> 9) & 1;
        int r = j >> 10;              // li*27 + tap
        int tap = r % 27, li = r / 27;
        int co = nt * 16 + (l & 15), ci = (l >> 4) * 8 + e;
        float v = wk[((li * 32 + co) * 32 + ci) * 27 + tap];
        wpk[j] = f2bf(v);
    }
}

// ---------------- zero the (z,y) halo rows of both padded buffers ----------------
__global__ __launch_bounds__(256) void k_halo(uint16_t* __restrict__ buf0,
                                              uint16_t* __restrict__ buf1) {
    int e = blockIdx.x;     // 0..387 edge rows
    int pz, py;
    if (e < 98) { pz = 0; py = e; }
    else if (e < 196) { pz = 97; py = e - 98; }
    else { int f = e - 196; pz = 1 + (f >> 1); py = (f & 1) ? 97 : 0; }
    uint16_t* buf = blockIdx.z ? buf1 : buf0;
    long long base = ((long long)blockIdx.y * PR + pz * 98 + py) * ROWE;
    uint4 z4 = make_uint4(0, 0, 0, 0);
    int t = threadIdx.x;
    *((uint4*)(buf + base) + t) = z4;
    if (t < 128) *((uint4*)(buf + base) + t + 256) = z4;
}

// ---------------- conv0: data fp32 -> padded chan-last raw bf16 + stat partials ----------------
// 192 threads = 3 waves; thread = (co, 16-x strip). Direct global reads (L1 broadcast).
__global__ __launch_bounds__(192) void k_conv0(const float* __restrict__ data,
        const float* __restrict__ wT0, uint16_t* __restrict__ out,
        float2* __restrict__ spart) {
    const int y = blockIdx.x, z = blockIdx.y, b = blockIdx.z;
    const int t = threadIdx.x, co = t & 31, xs = t >> 5;   // xs 0..5
    const int xb4 = 16 * xs - 4;
    __shared__ float ws[27 * 32];
    __shared__ float wpart[3][32][2];
    for (int i = t; i < 27 * 32; i += 192) ws[i] = wT0[i];
    __syncthreads();

    float acc[16];
#pragma unroll
    for (int j = 0; j < 16; ++j) acc[j] = 0.f;

#pragma unroll 3
    for (int row = 0; row < 9; ++row) {
        int dz = row / 3 - 1, dy = row % 3 - 1;
        int vz = z + dz, vy = y + dy;
        bool rowok = (vz >= 0 && vz < DD && vy >= 0 && vy < DD);
        const float* rp = data + (long long)b * VV + (long long)(vz * 96 + vy) * 96;
        float v[24];
#pragma unroll
        for (int k = 0; k < 6; ++k) {
            int start = xb4 + 4 * k;
            float4 f = make_float4(0.f, 0.f, 0.f, 0.f);
            if (rowok && start >= 0 && start <= 92) f = *(const float4*)(rp + start);
            v[4 * k] = f.x; v[4 * k + 1] = f.y; v[4 * k + 2] = f.z; v[4 * k + 3] = f.w;
        }
        float w0 = ws[(row * 3 + 0) * 32 + co];
        float w1 = ws[(row * 3 + 1) * 32 + co];
        float w2 = ws[(row * 3 + 2) * 32 + co];
#pragma unroll
        for (int j = 0; j < 16; ++j)
            acc[j] = fmaf(v[j + 3], w0, fmaf(v[j + 4], w1, fmaf(v[j + 5], w2, acc[j])));
    }
    // stats
    float s1 = 0.f, s2 = 0.f;
#pragma unroll
    for (int j = 0; j < 16; ++j) { s1 += acc[j]; s2 += acc[j] * acc[j]; }
    s1 += __shfl_xor(s1, 32, 64);
    s2 += __shfl_xor(s2, 32, 64);
    int wv = t >> 6;
    if ((t & 63) < 32) { wpart[wv][co][0] = s1; wpart[wv][co][1] = s2; }
    __syncthreads();
    if (t < 32) {
        float a = 0.f, c2 = 0.f;
#pragma unroll
        for (int w = 0; w < 3; ++w) { a += wpart[w][t][0]; c2 += wpart[w][t][1]; }
        int zone = z * 96 + y;
        spart[(zone * 2 + b) * 32 + t] = make_float2(a, c2);
    }
    // store raw bf16, padded chan-last
    long long rowbase = ((long long)b * PR + (z + 1) * 98 + (y + 1)) * ROWE;
#pragma unroll
    for (int j = 0; j < 16; ++j)
        out[rowbase + (16 * xs + j) * 32 + co] = f2bf(acc[j]);
}

// ---------------- stats finalize ----------------
__global__ void k_finalize(const float2* __restrict__ spart, float2* __restrict__ mr) {
    const int bc = blockIdx.x, t = threadIdx.x;
    float a = 0.f, s2 = 0.f;
    for (int z = t; z < 9216; z += 256) {
        float2 v = spart[z * 64 + bc];
        a += v.x; s2 += v.y;
    }
#pragma unroll
    for (int m = 1; m < 64; m <<= 1) {
        a  += __shfl_xor(a, m, 64);
        s2 += __shfl_xor(s2, m, 64);
    }
    __shared__ float2 wred[4];
    if ((t & 63) == 0) wred[t >> 6] = make_float2(a, s2);
    __syncthreads();
    if (t == 0) {
        float A = wred[0].x + wred[1].x + wred[2].x + wred[3].x;
        float S = wred[0].y + wred[1].y + wred[2].y + wred[3].y;
        float mean = A / (float)VV;
        float var = S / (float)VV - mean * mean;
        float rs = rsqrtf(fmaxf(var, 0.f) + EPSN);
        mr[bc] = make_float2(mean, rs);
    }
}

// ---------------- padded chan-last in-place normalize+relu (interior rows only) ----------------
__global__ __launch_bounds__(256) void k_prepass_cl(uint16_t* __restrict__ emb,
                                                    const float2* __restrict__ mr) {
    int row = blockIdx.x;               // 0..18431
    int b = row >= 9216 ? 1 : 0;
    int rr = row - b * 9216;
    int z = rr / 96, y = rr - z * 96;
    __shared__ float2 mrs[32];
    if (threadIdx.x < 32) mrs[threadIdx.x] = mr[b * 32 + threadIdx.x];
    __syncthreads();
    long long base = ((long long)b * PR + (z + 1) * 98 + (y + 1)) * ROWE;
    for (int chunk = threadIdx.x; chunk < 384; chunk += 256) {
        int g = chunk & 3;
        uint4* p = (uint4*)(emb + base + chunk * 8);
        uint4 raw = *p;
        uint32_t u[4] = {raw.x, raw.y, raw.z, raw.w};
        uint32_t o[4];
#pragma unroll
        for (int e = 0; e < 4; ++e) {
            float2 m0 = mrs[g * 8 + 2 * e];
            float2 m1 = mrs[g * 8 + 2 * e + 1];
            float lo = bf2f(u[e] & 0xFFFFu);
            union { uint32_t i; float f; } hi; hi.i = u[e] & 0xFFFF0000u;
            float a0 = fmaxf(0.f, (lo   - m0.x) * m0.y);
            float a1 = fmaxf(0.f, (hi.f - m1.x) * m1.y);
            o[e] = (uint32_t)f2bf(a0) | ((uint32_t)f2bf(a1) << 16);
        }
        *p = make_uint4(o[0], o[1], o[2], o[3]);
    }
}

// ---------------- MFMA convk: padded normalized chan-last in -> raw out + stat partials ----------
// 512 thr = 8 waves; wave = one (b,z,y) output row: 96 vox x 32 co. Branch-free 27-tap unroll.
template<int CHFIRST>
__global__ __launch_bounds__(512, 4) void k_convk_mfma(const uint16_t* __restrict__ in,
        const uint16_t* __restrict__ wpk, uint16_t* __restrict__ out,
        float2* __restrict__ spart) {
    __shared__ uint16_t wlds[27 * 2 * 512];
    const int t = threadIdx.x;
    for (int i = t; i < 27 * 2 * 512 / 8; i += 512)
        ((short8*)wlds)[i] = ((const short8*)wpk)[i];
    __syncthreads();

    int bid = (int)blockIdx.x;
    bid = (bid & 7) * 288 + (bid >> 3);   // XCD swizzle (2304 % 8 == 0)
    const int yg = bid % 12; int tmp = bid / 12;
    const int z = tmp % 96; const int b = tmp / 96;
    const int w = t >> 6, lane = t & 63;
    const int y = yg * 8 + w;
    const int vx = lane & 15, kg = lane >> 4;

    floatx4 acc[6][2];
#pragma unroll
    for (int mt = 0; mt < 6; ++mt) {
        acc[mt][0] = (floatx4){0.f, 0.f, 0.f, 0.f};
        acc[mt][1] = (floatx4){0.f, 0.f, 0.f, 0.f};
    }

    const uint16_t* inb = in + (long long)b * PR * ROWE;

#pragma unroll
    for (int dz = 0; dz < 3; ++dz) {
#pragma unroll
        for (int dy = 0; dy < 3; ++dy) {
            const uint16_t* rowp = inb + (long long)((z + dz) * 98 + (y + dy)) * ROWE;
            const int tap0 = (dz * 3 + dy) * 3;
#pragma unroll
            for (int dx = 0; dx < 3; ++dx) {
                const int toff = (tap0 + dx) * 1024;
                const short8 wb0 = *(const short8*)&wlds[toff + lane * 8];
                const short8 wb1 = *(const short8*)&wlds[toff + 512 + lane * 8];
#pragma unroll
                for (int mt = 0; mt < 6; ++mt) {
                    int x = mt * 16 + vx + dx - 1;
                    short8 a;
                    if ((mt == 0 && dx == 0) || (mt == 5 && dx == 2)) {
                        int xc = min(max(x, 0), 95);
                        a = *(const short8*)&rowp[xc * 32 + kg * 8];
                        if (x != xc) {
                            short8 zz = {0, 0, 0, 0, 0, 0, 0, 0};
                            a = zz;
                        }
                    } else {
                        a = *(const short8*)&rowp[x * 32 + kg * 8];
                    }
                    acc[mt][0] = __builtin_amdgcn_mfma_f32_16x16x32_bf16(a, wb0, acc[mt][0], 0, 0, 0);
                    acc[mt][1] = __builtin_amdgcn_mfma_f32_16x16x32_bf16(a, wb1, acc[mt][1], 0, 0, 0);
                }
            }
        }
    }

    float s1n0 = 0.f, s2n0 = 0.f, s1n1 = 0.f, s2n1 = 0.f;
#pragma unroll
    for (int mt = 0; mt < 6; ++mt)
#pragma unroll
        for (int j = 0; j < 4; ++j) {
            float v0 = acc[mt][0][j], v1 = acc[mt][1][j];
            s1n0 += v0; s2n0 += v0 * v0;
            s1n1 += v1; s2n1 += v1 * v1;
        }
    s1n0 += __shfl_xor(s1n0, 16, 64); s1n0 += __shfl_xor(s1n0, 32, 64);
    s2n0 += __shfl_xor(s2n0, 16, 64); s2n0 += __shfl_xor(s2n0, 32, 64);
    s1n1 += __shfl_xor(s1n1, 16, 64); s1n1 += __shfl_xor(s1n1, 32, 64);
    s2n1 += __shfl_xor(s2n1, 16, 64); s2n1 += __shfl_xor(s2n1, 32, 64);
    if (lane < 16) {
        int zone = z * 96 + y;
        spart[(zone * 2 + b) * 32 + lane]      = make_float2(s1n0, s2n0);
        spart[(zone * 2 + b) * 32 + lane + 16] = make_float2(s1n1, s2n1);
    }

    if (CHFIRST) {
        // unpadded chan-first raw: out[(b*32+co)*VV + vox]
        long long vbase = (long long)(z * 96 + y) * 96;
#pragma unroll
        for (int mt = 0; mt < 6; ++mt)
#pragma unroll
            for (int nt = 0; nt < 2; ++nt) {
                uint32_t lo = (uint32_t)f2bf(acc[mt][nt][0]) | ((uint32_t)f2bf(acc[mt][nt][1]) << 16);
                uint32_t hi = (uint32_t)f2bf(acc[mt][nt][2]) | ((uint32_t)f2bf(acc[mt][nt][3]) << 16);
                long long co = b * 32 + nt * 16 + vx;
                uint2* dst = (uint2*)&out[co * VV + vbase + mt * 16 + kg * 4];
                *dst = make_uint2(lo, hi);
            }
    } else {
        // padded chan-last raw
        long long obase = ((long long)b * PR + (z + 1) * 98 + (y + 1)) * ROWE;
#pragma unroll
        for (int mt = 0; mt < 6; ++mt)
#pragma unroll
            for (int nt = 0; nt < 2; ++nt)
#pragma unroll
                for (int j = 0; j < 4; ++j)
                    out[obase + (long long)(mt * 16 + kg * 4 + j) * 32 + nt * 16 + vx] =
                        f2bf(acc[mt][nt][j]);
    }
}

// ---------------- MFMA pooling with fused instance-norm+relu ----------------
// grid = 432 zones (2048 vox); block = 448 thr = 7 waves.
__global__ __launch_bounds__(448) void k_pool_mfma(const uint16_t* __restrict__ emb,
        const float* __restrict__ mask, const float2* __restrict__ mr,
        float* __restrict__ rzone, float* __restrict__ mzone) {
    const int t = threadIdx.x;
    const int rt = t >> 6, lane = t & 63;
    const int rl = lane & 15, kq = lane >> 4;
    const int r = rt * 16 + rl;
    const int rc = min(r, 99);
    const long long v0 = (long long)blockIdx.x * 2048;

    float nA[4], nB[4];
#pragma unroll
    for (int bct = 0; bct < 4; ++bct) {
        float2 v = mr[bct * 16 + rl];
        nA[bct] = v.y;
        nB[bct] = -v.x * v.y;
    }

    floatx4 acc[4];
#pragma unroll
    for (int bct = 0; bct < 4; ++bct) acc[bct] = (floatx4){0.f, 0.f, 0.f, 0.f};
    float msum = 0.f;

    const float* mrow = mask + (long long)rc * VV + v0 + kq * 8;
    const uint16_t* eb0 = emb + (long long)(0 * 16 + rl) * VV + v0 + kq * 8;
    const uint16_t* eb1 = emb + (long long)(1 * 16 + rl) * VV + v0 + kq * 8;
    const uint16_t* eb2 = emb + (long long)(2 * 16 + rl) * VV + v0 + kq * 8;
    const uint16_t* eb3 = emb + (long long)(3 * 16 + rl) * VV + v0 + kq * 8;
    const uint16_t* ebase[4] = {eb0, eb1, eb2, eb3};

#pragma unroll 2
    for (int ks = 0; ks < 64; ++ks) {
        const float4 a0 = *(const float4*)(mrow + ks * 32);
        const float4 a1 = *(const float4*)(mrow + ks * 32 + 4);
        msum += (a0.x + a0.y + a0.z + a0.w) + (a1.x + a1.y + a1.z + a1.w);
        union { uint32_t u[4]; short8 s; } af;
        af.u[0] = cvtpk(a0.x, a0.y);
        af.u[1] = cvtpk(a0.z, a0.w);
        af.u[2] = cvtpk(a1.x, a1.y);
        af.u[3] = cvtpk(a1.z, a1.w);
#pragma unroll
        for (int bct = 0; bct < 4; ++bct) {
            uint4 raw = *(const uint4*)(ebase[bct] + ks * 32);
            uint32_t u[4] = {raw.x, raw.y, raw.z, raw.w};
            union { uint32_t u[4]; short8 s; } bfr;
#pragma unroll
            for (int e = 0; e < 4; ++e) {
                float lo = bf2f(u[e] & 0xFFFFu);
                union { uint32_t i; float f; } hv; hv.i = u[e] & 0xFFFF0000u;
                float x0 = fmaxf(0.f, fmaf(lo,   nA[bct], nB[bct]));
                float x1 = fmaxf(0.f, fmaf(hv.f, nA[bct], nB[bct]));
                bfr.u[e] = cvtpk(x0, x1);
            }
            acc[bct] = __builtin_amdgcn_mfma_f32_16x16x32_bf16(af.s, bfr.s, acc[bct], 0, 0, 0);
        }
    }

    msum += __shfl_xor(msum, 16, 64);
    msum += __shfl_xor(msum, 32, 64);
    if (lane < 16 && r < 100)
        mzone[blockIdx.x * 100 + r] = msum;

#pragma unroll
    for (int bct = 0; bct < 4; ++bct)
#pragma unroll
        for (int reg = 0; reg < 4; ++reg) {
            int rr = rt * 16 + kq * 4 + reg;
            if (rr < 100)
                rzone[((long long)blockIdx.x * 100 + rr) * 64 + bct * 16 + rl] = acc[bct][reg];
        }
}

// ---------------- roi finalize ----------------
__global__ void k_roifin(const float* __restrict__ rzone, const float* __restrict__ mzone,
                         float* __restrict__ roi) {
    const int r = blockIdx.x, t = threadIdx.x;
    __shared__ float sred[256];
    float ms = 0.f;
    for (int z = t; z < 432; z += 256) ms += mzone[z * 100 + r];
    sred[t] = ms;
    __syncthreads();
    for (int s = 128; s > 0; s >>= 1) {
        if (t < s) sred[t] += sred[t + s];
        __syncthreads();
    }
    float msum = sred[0];
    const int bc = t & 63, zs = t >> 6;
    float a = 0.f;
    for (int z = zs; z < 432; z += 4) a += rzone[((long long)z * 100 + r) * 64 + bc];
    __shared__ float s2[4][64];
    s2[zs][bc] = a;
    __syncthreads();
    if (t < 64) {
        float v = s2[0][t] + s2[1][t] + s2[2][t] + s2[3][t];
        int b = t >> 5, c = t & 31;
        roi[(b * 100 + r) * 32 + c] = v / msum;
    }
}

// ---------------- per-ROI MLPs ----------------
__global__ __launch_bounds__(256) void k_mlp(const float* __restrict__ roi,
        const float* __restrict__ sw1, const float* __restrict__ sb1,
        const float* __restrict__ sw2, const float* __restrict__ sb2,
        const float* __restrict__ pw1, const float* __restrict__ pb1,
        const float* __restrict__ pw2, const float* __restrict__ pb2,
        float* __restrict__ outp) {
    const int r = blockIdx.x, b = blockIdx.y, t = threadIdx.x;
    __shared__ float roi_s[32], h1_s[64], sf_s[32], h2_s[256], part[128];
    if (t < 32) roi_s[t] = roi[(b * 100 + r) * 32 + t];
    __syncthreads();
    if (t < 64) {
        float a = sb1[r * 64 + t];
        for (int c = 0; c < 32; ++c) a += roi_s[c] * sw1[(r * 32 + c) * 64 + t];
        h1_s[t] = fmaxf(a, 0.f);
    }
    __syncthreads();
    if (t < 32) {
        float a = sb2[r * 32 + t];
        for (int h = 0; h < 64; ++h) a += h1_s[h] * sw2[(r * 64 + h) * 32 + t];
        float sg = 1.f / (1.f + expf(-a));
        sf_s[t] = sg * roi_s[t];
    }
    __syncthreads();
    {
        float a = pb1[r * 256 + t];
        for (int c = 0; c < 32; ++c) a += sf_s[c] * pw1[(r * 32 + c) * 256 + t];
        h2_s[t] = fmaxf(a, 0.f);
    }
    __syncthreads();
    {
        const int e = t & 127, hh = t >> 7;
        float a = 0.f;
        for (int h = hh * 128; h < hh * 128 + 128; ++h)
            a += h2_s[h] * pw2[(r * 256 + h) * 128 + e];
        if (hh) part[e] = a;
        __syncthreads();
        if (t < 128) outp[(b * 100 + r) * 128 + t] = part[t] + a + pb2[r * 128 + t];
    }
}

extern "C" void kernel_launch(void* const* d_in, const int* in_sizes, int n_in,
                              void* d_out, int out_size, void* d_ws, size_t ws_size,
                              hipStream_t stream) {
    const float* data = (const float*)d_in[0];
    const float* mask = (const float*)d_in[1];
    const float* w0   = (const float*)d_in[2];
    const float* wk   = (const float*)d_in[4];
    const float* sw1  = (const float*)d_in[6];
    const float* sb1  = (const float*)d_in[7];
    const float* sw2  = (const float*)d_in[8];
    const float* sb2  = (const float*)d_in[9];
    const float* pw1  = (const float*)d_in[10];
    const float* pb1  = (const float*)d_in[11];
    const float* pw2  = (const float*)d_in[12];
    const float* pb2  = (const float*)d_in[13];
    float* out = (float*)d_out;

    char* ws = (char*)d_ws;
    size_t off = 0;
    auto alloc = [&](size_t bytes) {
        void* p = ws + off;
        off += (bytes + 255) & ~(size_t)255;
        return p;
    };
    uint16_t* buf0 = (uint16_t*)alloc((size_t)2 * PR * ROWE * 2);
    uint16_t* buf1 = (uint16_t*)alloc((size_t)2 * PR * ROWE * 2);
    uint16_t* bufcf = buf1;   // chan-first final output aliases buf1 storage
    float* wT0     = (float*)alloc(27 * 32 * 4);
    uint16_t* wpk  = (uint16_t*)alloc((size_t)3 * 27 * 2 * 512 * 2);
    float2* spart  = (float2*)alloc((size_t)9216 * 2 * 32 * 8);
    float2* mr     = (float2*)alloc(4 * 64 * 8);
    float* rzone   = (float*)alloc((size_t)432 * 100 * 64 * 4);
    float* mzone   = (float*)alloc((size_t)432 * 100 * 4);
    float* roi     = (float*)alloc(2 * 100 * 32 * 4);
    (void)ws_size; (void)in_sizes; (void)n_in; (void)out_size;

    k_packw<<<328, 256, 0, stream>>>(w0, wk, wT0, wpk);
    k_halo<<<dim3(388, 2, 2), 256, 0, stream>>>(buf0, buf1);

    dim3 cgrid(96, 96, 2);
    k_conv0<<<cgrid, 192, 0, stream>>>(data, wT0, buf0, spart);
    k_finalize<<<64, 256, 0, stream>>>((const float2*)spart, mr + 0);
    k_prepass_cl<<<18432, 256, 0, stream>>>(buf0, mr + 0);

    k_convk_mfma<0><<<2304, 512, 0, stream>>>(buf0, wpk + 0 * 27648, buf1, spart);
    k_finalize<<<64, 256, 0, stream>>>((const float2*)spart, mr + 64);
    k_prepass_cl<<<18432, 256, 0, stream>>>(buf1, mr + 64);

    k_convk_mfma<0><<<2304, 512, 0, stream>>>(buf1, wpk + 1 * 27648, buf0, spart);
    k_finalize<<<64, 256, 0, stream>>>((const float2*)spart, mr + 128);
    k_prepass_cl<<<18432, 256, 0, stream>>>(buf0, mr + 128);

    k_convk_mfma<1><<<2304, 512, 0, stream>>>(buf0, wpk + 2 * 27648, bufcf, spart);
    k_finalize<<<64, 256, 0, stream>>>((const float2*)spart, mr + 192);

    k_pool_mfma<<<432, 448, 0, stream>>>(bufcf, mask, mr + 192, rzone, mzone);
    k_roifin<<<100, 256, 0, stream>>>(rzone, mzone, roi);

    k_mlp<<<dim3(100, 2), 256, 0, stream>>>(roi, sw1, sb1, sw2, sb2,
                                            pw1, pb1, pw2, pb2, out);
}

// Round 5
// 919.769 us; speedup vs baseline: 1.3554x; 1.3554x over previous
//
#include <hip/hip_runtime.h>
#include <stdint.h>

#define DD 96
#define VV (96*96*96)   // 884736
#define EPSN 1e-5f

typedef short short8 __attribute__((ext_vector_type(8)));
typedef float floatx4 __attribute__((ext_vector_type(4)));

__device__ __forceinline__ float bf2f(uint32_t u_lo16) {
    union { uint32_t i; float f; } x; x.i = u_lo16 << 16; return x.f;
}
__device__ __forceinline__ uint16_t f2bf(float f) {
    union { float f; uint32_t i; } x; x.f = f;
    uint32_t r = x.i + 0x7FFFu + ((x.i >> 16) & 1u);
    return (uint16_t)(r >> 16);
}
__device__ __forceinline__ uint32_t cvtpk(float lo, float hi) {
    uint32_t r;
    asm("v_cvt_pk_bf16_f32 %0, %1, %2" : "=v"(r) : "v"(lo), "v"(hi));
    return r;
}

// ---------------- weight packing ----------------
// wT0 [k][co] fp32 for conv0.
// wpk[((li*27+tap)*2+nt)*512 + l*8 + e] = wk[li][co=nt*16+(l&15)][ci=(l>>4)*8+e][tap]
__global__ void k_packw(const float* __restrict__ w0, const float* __restrict__ wk,
                        float* __restrict__ wT0, uint16_t* __restrict__ wpk) {
    int i = blockIdx.x * 256 + threadIdx.x;
    if (i < 27 * 32) {
        int co = i / 27, k = i % 27;
        wT0[k * 32 + co] = w0[i];
    }
    int j = i - 27 * 32;
    if (j >= 0 && j < 3 * 27 * 2 * 512) {
        int e = j & 7, l = (j >> 3) & 63, nt = (j >> 9) & 1;
        int r = j >> 10;              // li*27 + tap
        int tap = r % 27, li = r / 27;
        int co = nt * 16 + (l & 15), ci = (l >> 4) * 8 + e;
        float v = wk[((li * 32 + co) * 32 + ci) * 27 + tap];
        wpk[j] = f2bf(v);
    }
}

// ---------------- conv0: data fp32 -> unpadded chan-last raw bf16 + stat partials ----------------
__global__ __launch_bounds__(192) void k_conv0(const float* __restrict__ data,
        const float* __restrict__ wT0, uint16_t* __restrict__ out,
        float2* __restrict__ spart) {
    const int y = blockIdx.x, z = blockIdx.y, b = blockIdx.z;
    const int t = threadIdx.x, co = t & 31, xs = t >> 5;   // xs 0..5
    const int xb4 = 16 * xs - 4;
    __shared__ float ws[27 * 32];
    __shared__ float wpart[3][32][2];
    for (int i = t; i < 27 * 32; i += 192) ws[i] = wT0[i];
    __syncthreads();

    float acc[16];
#pragma unroll
    for (int j = 0; j < 16; ++j) acc[j] = 0.f;

#pragma unroll 3
    for (int row = 0; row < 9; ++row) {
        int dz = row / 3 - 1, dy = row % 3 - 1;
        int vz = z + dz, vy = y + dy;
        bool rowok = (vz >= 0 && vz < DD && vy >= 0 && vy < DD);
        const float* rp = data + (long long)b * VV + (long long)(vz * 96 + vy) * 96;
        float v[24];
#pragma unroll
        for (int k = 0; k < 6; ++k) {
            int start = xb4 + 4 * k;
            float4 f = make_float4(0.f, 0.f, 0.f, 0.f);
            if (rowok && start >= 0 && start <= 92) f = *(const float4*)(rp + start);
            v[4 * k] = f.x; v[4 * k + 1] = f.y; v[4 * k + 2] = f.z; v[4 * k + 3] = f.w;
        }
        float w0 = ws[(row * 3 + 0) * 32 + co];
        float w1 = ws[(row * 3 + 1) * 32 + co];
        float w2 = ws[(row * 3 + 2) * 32 + co];
#pragma unroll
        for (int j = 0; j < 16; ++j)
            acc[j] = fmaf(v[j + 3], w0, fmaf(v[j + 4], w1, fmaf(v[j + 5], w2, acc[j])));
    }
    float s1 = 0.f, s2 = 0.f;
#pragma unroll
    for (int j = 0; j < 16; ++j) { s1 += acc[j]; s2 += acc[j] * acc[j]; }
    s1 += __shfl_xor(s1, 32, 64);
    s2 += __shfl_xor(s2, 32, 64);
    int wv = t >> 6;
    if ((t & 63) < 32) { wpart[wv][co][0] = s1; wpart[wv][co][1] = s2; }
    __syncthreads();
    if (t < 32) {
        float a = 0.f, c2 = 0.f;
#pragma unroll
        for (int w = 0; w < 3; ++w) { a += wpart[w][t][0]; c2 += wpart[w][t][1]; }
        int zone = z * 96 + y;
        spart[(zone * 2 + b) * 32 + t] = make_float2(a, c2);
    }
    long long obase = ((long long)b * VV + (long long)(z * 96 + y) * 96 + 16 * xs) * 32 + co;
#pragma unroll
    for (int j = 0; j < 16; ++j)
        out[obase + (long long)j * 32] = f2bf(acc[j]);
}

// ---------------- stats finalize ----------------
__global__ void k_finalize(const float2* __restrict__ spart, float2* __restrict__ mr) {
    const int bc = blockIdx.x, t = threadIdx.x;
    float a = 0.f, s2 = 0.f;
    for (int z = t; z < 9216; z += 256) {
        float2 v = spart[z * 64 + bc];
        a += v.x; s2 += v.y;
    }
#pragma unroll
    for (int m = 1; m < 64; m <<= 1) {
        a  += __shfl_xor(a, m, 64);
        s2 += __shfl_xor(s2, m, 64);
    }
    __shared__ float2 wred[4];
    if ((t & 63) == 0) wred[t >> 6] = make_float2(a, s2);
    __syncthreads();
    if (t == 0) {
        float A = wred[0].x + wred[1].x + wred[2].x + wred[3].x;
        float S = wred[0].y + wred[1].y + wred[2].y + wred[3].y;
        float mean = A / (float)VV;
        float var = S / (float)VV - mean * mean;
        float rs = rsqrtf(fmaxf(var, 0.f) + EPSN);
        mr[bc] = make_float2(mean, rs);
    }
}

// ---------------- MFMA convk v3: LDS-staged rows, normalize fused into staging ----------------
// block = 512 thr = 8 waves = one z x 8 y output rows (96 vox x 32 co each).
// Per dz: stage 10 input rows (98 vox x 32 ci, x-halo zeros, norm+relu applied) into LDS,
// then 9 (dy,dx) taps read A-frags from LDS; weights (B) read direct from global (L1/L2-hot).
template<int CHFIRST>
__global__ __launch_bounds__(512, 4) void k_convk_v3(const uint16_t* __restrict__ in,
        const float2* __restrict__ mrprev, const uint16_t* __restrict__ wpk,
        uint16_t* __restrict__ out, float2* __restrict__ spart) {
    __shared__ uint16_t a_s[10 * 3136];   // 10 rows x 98 vox x 32 ci = 62720 B

    int bid = (int)blockIdx.x;
    bid = (bid & 7) * 288 + (bid >> 3);   // XCD swizzle (2304 % 8 == 0)
    const int yg = bid % 12; int tmp = bid / 12;
    const int z = tmp % 96; const int b = tmp / 96;
    const int t = threadIdx.x;
    const int w = t >> 6, lane = t & 63;
    const int y = yg * 8 + w;
    const int vx = lane & 15, kg = lane >> 4;

    // staging role: thread owns channel group cig (8 ci), voxel-slot stride 128
    const int cig = t & 3, vgrp = t >> 2;
    float nAr[8], nBr[8];
#pragma unroll
    for (int e = 0; e < 8; ++e) {
        float2 v = mrprev[b * 32 + cig * 8 + e];
        nAr[e] = v.y;             // rs
        nBr[e] = -v.x * v.y;      // -m*rs
    }

    // zero x-halo slots (vox 0 and vox 97 of each row) once
    if (t < 160) {
        int row = t >> 4, half = (t >> 3) & 1, o8 = t & 7;
        *((uint2*)&a_s[row * 3136 + (half ? 97 * 32 : 0) + o8 * 4]) = make_uint2(0, 0);
    }

    floatx4 acc[6][2];
#pragma unroll
    for (int mt = 0; mt < 6; ++mt) {
        acc[mt][0] = (floatx4){0.f, 0.f, 0.f, 0.f};
        acc[mt][1] = (floatx4){0.f, 0.f, 0.f, 0.f};
    }

    const uint16_t* inb = in + (long long)b * VV * 32;

    for (int dz = 0; dz < 3; ++dz) {
        const int zp = z + dz - 1;
        const bool zok = (unsigned)zp < 96u;
        __syncthreads();   // previous compute done before overwrite
        // ---- stage 10 rows: 960 vox-slots, thread does slots vgrp + j*128 ----
#pragma unroll
        for (int j = 0; j < 8; ++j) {
            int v = vgrp + j * 128;
            if (v < 960) {
                int row = v / 96;
                int x = v - row * 96;
                int yp = yg * 8 + row - 1;
                uint4 o4 = make_uint4(0, 0, 0, 0);
                if (zok && (unsigned)yp < 96u) {
                    uint4 raw = *(const uint4*)(inb +
                        (((long long)zp * 96 + yp) * 96 + x) * 32 + cig * 8);
                    uint32_t u[4] = {raw.x, raw.y, raw.z, raw.w};
#pragma unroll
                    for (int e = 0; e < 4; ++e) {
                        float lo = bf2f(u[e] & 0xFFFFu);
                        union { uint32_t i; float f; } hv; hv.i = u[e] & 0xFFFF0000u;
                        float x0 = fmaxf(0.f, fmaf(lo,   nAr[2 * e],     nBr[2 * e]));
                        float x1 = fmaxf(0.f, fmaf(hv.f, nAr[2 * e + 1], nBr[2 * e + 1]));
                        o4.x = e == 0 ? cvtpk(x0, x1) : o4.x;
                        o4.y = e == 1 ? cvtpk(x0, x1) : o4.y;
                        o4.z = e == 2 ? cvtpk(x0, x1) : o4.z;
                        o4.w = e == 3 ? cvtpk(x0, x1) : o4.w;
                    }
                }
                *((uint4*)&a_s[row * 3136 + (x + 1) * 32 + cig * 8]) = o4;
            }
        }
        __syncthreads();
        // ---- compute: 9 taps of this dz ----
        const uint16_t* wpt = wpk + dz * 9216;   // 9 taps x 2 nt x 512
#pragma unroll
        for (int dy = 0; dy < 3; ++dy) {
            const uint16_t* as_row = &a_s[(w + dy) * 3136];
#pragma unroll
            for (int dx = 0; dx < 3; ++dx) {
                const int tl = dy * 3 + dx;
                const short8 wb0 = *(const short8*)&wpt[(tl * 2 + 0) * 512 + lane * 8];
                const short8 wb1 = *(const short8*)&wpt[(tl * 2 + 1) * 512 + lane * 8];
#pragma unroll
                for (int mt = 0; mt < 6; ++mt) {
                    const short8 a = *(const short8*)&as_row[(mt * 16 + vx + dx) * 32 + kg * 8];
                    acc[mt][0] = __builtin_amdgcn_mfma_f32_16x16x32_bf16(a, wb0, acc[mt][0], 0, 0, 0);
                    acc[mt][1] = __builtin_amdgcn_mfma_f32_16x16x32_bf16(a, wb1, acc[mt][1], 0, 0, 0);
                }
            }
        }
    }

    // stats on raw outputs
    float s1n0 = 0.f, s2n0 = 0.f, s1n1 = 0.f, s2n1 = 0.f;
#pragma unroll
    for (int mt = 0; mt < 6; ++mt)
#pragma unroll
        for (int j = 0; j < 4; ++j) {
            float v0 = acc[mt][0][j], v1 = acc[mt][1][j];
            s1n0 += v0; s2n0 += v0 * v0;
            s1n1 += v1; s2n1 += v1 * v1;
        }
    s1n0 += __shfl_xor(s1n0, 16, 64); s1n0 += __shfl_xor(s1n0, 32, 64);
    s2n0 += __shfl_xor(s2n0, 16, 64); s2n0 += __shfl_xor(s2n0, 32, 64);
    s1n1 += __shfl_xor(s1n1, 16, 64); s1n1 += __shfl_xor(s1n1, 32, 64);
    s2n1 += __shfl_xor(s2n1, 16, 64); s2n1 += __shfl_xor(s2n1, 32, 64);
    if (lane < 16) {
        int zone = z * 96 + y;
        spart[(zone * 2 + b) * 32 + lane]      = make_float2(s1n0, s2n0);
        spart[(zone * 2 + b) * 32 + lane + 16] = make_float2(s1n1, s2n1);
    }

    if (CHFIRST) {
        // chan-first raw: out[(b*32+co)*VV + vox]
        long long vbase = (long long)(z * 96 + y) * 96;
#pragma unroll
        for (int mt = 0; mt < 6; ++mt)
#pragma unroll
            for (int nt = 0; nt < 2; ++nt) {
                uint32_t lo = (uint32_t)f2bf(acc[mt][nt][0]) | ((uint32_t)f2bf(acc[mt][nt][1]) << 16);
                uint32_t hi = (uint32_t)f2bf(acc[mt][nt][2]) | ((uint32_t)f2bf(acc[mt][nt][3]) << 16);
                long long co = b * 32 + nt * 16 + vx;
                uint2* dst = (uint2*)&out[co * VV + vbase + mt * 16 + kg * 4];
                *dst = make_uint2(lo, hi);
            }
    } else {
        // unpadded chan-last raw: out[(b*VV + vox)*32 + co]
        long long obase = ((long long)b * VV + (long long)(z * 96 + y) * 96) * 32;
#pragma unroll
        for (int mt = 0; mt < 6; ++mt)
#pragma unroll
            for (int nt = 0; nt < 2; ++nt)
#pragma unroll
                for (int j = 0; j < 4; ++j)
                    out[obase + (long long)(mt * 16 + kg * 4 + j) * 32 + nt * 16 + vx] =
                        f2bf(acc[mt][nt][j]);
    }
}

// ---------------- MFMA pooling with fused instance-norm+relu ----------------
// grid = 432 zones (2048 vox); block = 448 thr = 7 waves.
__global__ __launch_bounds__(448) void k_pool_mfma(const uint16_t* __restrict__ emb,
        const float* __restrict__ mask, const float2* __restrict__ mr,
        float* __restrict__ rzone, float* __restrict__ mzone) {
    const int t = threadIdx.x;
    const int rt = t >> 6, lane = t & 63;
    const int rl = lane & 15, kq = lane >> 4;
    const int r = rt * 16 + rl;
    const int rc = min(r, 99);
    const long long v0 = (long long)blockIdx.x * 2048;

    float nA[4], nB[4];
#pragma unroll
    for (int bct = 0; bct < 4; ++bct) {
        float2 v = mr[bct * 16 + rl];
        nA[bct] = v.y;
        nB[bct] = -v.x * v.y;
    }

    floatx4 acc[4];
#pragma unroll
    for (int bct = 0; bct < 4; ++bct) acc[bct] = (floatx4){0.f, 0.f, 0.f, 0.f};
    float msum = 0.f;

    const float* mrow = mask + (long long)rc * VV + v0 + kq * 8;
    const uint16_t* eb0 = emb + (long long)(0 * 16 + rl) * VV + v0 + kq * 8;
    const uint16_t* eb1 = emb + (long long)(1 * 16 + rl) * VV + v0 + kq * 8;
    const uint16_t* eb2 = emb + (long long)(2 * 16 + rl) * VV + v0 + kq * 8;
    const uint16_t* eb3 = emb + (long long)(3 * 16 + rl) * VV + v0 + kq * 8;
    const uint16_t* ebase[4] = {eb0, eb1, eb2, eb3};

#pragma unroll 2
    for (int ks = 0; ks < 64; ++ks) {
        const float4 a0 = *(const float4*)(mrow + ks * 32);
        const float4 a1 = *(const float4*)(mrow + ks * 32 + 4);
        msum += (a0.x + a0.y + a0.z + a0.w) + (a1.x + a1.y + a1.z + a1.w);
        union { uint32_t u[4]; short8 s; } af;
        af.u[0] = cvtpk(a0.x, a0.y);
        af.u[1] = cvtpk(a0.z, a0.w);
        af.u[2] = cvtpk(a1.x, a1.y);
        af.u[3] = cvtpk(a1.z, a1.w);
#pragma unroll
        for (int bct = 0; bct < 4; ++bct) {
            uint4 raw = *(const uint4*)(ebase[bct] + ks * 32);
            uint32_t u[4] = {raw.x, raw.y, raw.z, raw.w};
            union { uint32_t u[4]; short8 s; } bfr;
#pragma unroll
            for (int e = 0; e < 4; ++e) {
                float lo = bf2f(u[e] & 0xFFFFu);
                union { uint32_t i; float f; } hv; hv.i = u[e] & 0xFFFF0000u;
                float x0 = fmaxf(0.f, fmaf(lo,   nA[bct], nB[bct]));
                float x1 = fmaxf(0.f, fmaf(hv.f, nA[bct], nB[bct]));
                bfr.u[e] = cvtpk(x0, x1);
            }
            acc[bct] = __builtin_amdgcn_mfma_f32_16x16x32_bf16(af.s, bfr.s, acc[bct], 0, 0, 0);
        }
    }

    msum += __shfl_xor(msum, 16, 64);
    msum += __shfl_xor(msum, 32, 64);
    if (lane < 16 && r < 100)
        mzone[blockIdx.x * 100 + r] = msum;

#pragma unroll
    for (int bct = 0; bct < 4; ++bct)
#pragma unroll
        for (int reg = 0; reg < 4; ++reg) {
            int rr = rt * 16 + kq * 4 + reg;
            if (rr < 100)
                rzone[((long long)blockIdx.x * 100 + rr) * 64 + bct * 16 + rl] = acc[bct][reg];
        }
}

// ---------------- roi finalize ----------------
__global__ void k_roifin(const float* __restrict__ rzone, const float* __restrict__ mzone,
                         float* __restrict__ roi) {
    const int r = blockIdx.x, t = threadIdx.x;
    __shared__ float sred[256];
    float ms = 0.f;
    for (int z = t; z < 432; z += 256) ms += mzone[z * 100 + r];
    sred[t] = ms;
    __syncthreads();
    for (int s = 128; s > 0; s >>= 1) {
        if (t < s) sred[t] += sred[t + s];
        __syncthreads();
    }
    float msum = sred[0];
    const int bc = t & 63, zs = t >> 6;
    float a = 0.f;
    for (int z = zs; z < 432; z += 4) a += rzone[((long long)z * 100 + r) * 64 + bc];
    __shared__ float s2[4][64];
    s2[zs][bc] = a;
    __syncthreads();
    if (t < 64) {
        float v = s2[0][t] + s2[1][t] + s2[2][t] + s2[3][t];
        int b = t >> 5, c = t & 31;
        roi[(b * 100 + r) * 32 + c] = v / msum;
    }
}

// ---------------- per-ROI MLPs ----------------
__global__ __launch_bounds__(256) void k_mlp(const float* __restrict__ roi,
        const float* __restrict__ sw1, const float* __restrict__ sb1,
        const float* __restrict__ sw2, const float* __restrict__ sb2,
        const float* __restrict__ pw1, const float* __restrict__ pb1,
        const float* __restrict__ pw2, const float* __restrict__ pb2,
        float* __restrict__ outp) {
    const int r = blockIdx.x, b = blockIdx.y, t = threadIdx.x;
    __shared__ float roi_s[32], h1_s[64], sf_s[32], h2_s[256], part[128];
    if (t < 32) roi_s[t] = roi[(b * 100 + r) * 32 + t];
    __syncthreads();
    if (t < 64) {
        float a = sb1[r * 64 + t];
        for (int c = 0; c < 32; ++c) a += roi_s[c] * sw1[(r * 32 + c) * 64 + t];
        h1_s[t] = fmaxf(a, 0.f);
    }
    __syncthreads();
    if (t < 32) {
        float a = sb2[r * 32 + t];
        for (int h = 0; h < 64; ++h) a += h1_s[h] * sw2[(r * 64 + h) * 32 + t];
        float sg = 1.f / (1.f + expf(-a));
        sf_s[t] = sg * roi_s[t];
    }
    __syncthreads();
    {
        float a = pb1[r * 256 + t];
        for (int c = 0; c < 32; ++c) a += sf_s[c] * pw1[(r * 32 + c) * 256 + t];
        h2_s[t] = fmaxf(a, 0.f);
    }
    __syncthreads();
    {
        const int e = t & 127, hh = t >> 7;
        float a = 0.f;
        for (int h = hh * 128; h < hh * 128 + 128; ++h)
            a += h2_s[h] * pw2[(r * 256 + h) * 128 + e];
        if (hh) part[e] = a;
        __syncthreads();
        if (t < 128) outp[(b * 100 + r) * 128 + t] = part[t] + a + pb2[r * 128 + t];
    }
}

extern "C" void kernel_launch(void* const* d_in, const int* in_sizes, int n_in,
                              void* d_out, int out_size, void* d_ws, size_t ws_size,
                              hipStream_t stream) {
    const float* data = (const float*)d_in[0];
    const float* mask = (const float*)d_in[1];
    const float* w0   = (const float*)d_in[2];
    const float* wk   = (const float*)d_in[4];
    const float* sw1  = (const float*)d_in[6];
    const float* sb1  = (const float*)d_in[7];
    const float* sw2  = (const float*)d_in[8];
    const float* sb2  = (const float*)d_in[9];
    const float* pw1  = (const float*)d_in[10];
    const float* pb1  = (const float*)d_in[11];
    const float* pw2  = (const float*)d_in[12];
    const float* pb2  = (const float*)d_in[13];
    float* out = (float*)d_out;

    char* ws = (char*)d_ws;
    size_t off = 0;
    auto alloc = [&](size_t bytes) {
        void* p = ws + off;
        off += (bytes + 255) & ~(size_t)255;
        return p;
    };
    uint16_t* buf0 = (uint16_t*)alloc((size_t)2 * VV * 32 * 2);
    uint16_t* buf1 = (uint16_t*)alloc((size_t)2 * VV * 32 * 2);
    float* wT0     = (float*)alloc(27 * 32 * 4);
    uint16_t* wpk  = (uint16_t*)alloc((size_t)3 * 27 * 2 * 512 * 2);
    float2* spart  = (float2*)alloc((size_t)9216 * 2 * 32 * 8);
    float2* mr     = (float2*)alloc(4 * 64 * 8);
    float* rzone   = (float*)alloc((size_t)432 * 100 * 64 * 4);
    float* mzone   = (float*)alloc((size_t)432 * 100 * 4);
    float* roi     = (float*)alloc(2 * 100 * 32 * 4);
    (void)ws_size; (void)in_sizes; (void)n_in; (void)out_size;

    k_packw<<<328, 256, 0, stream>>>(w0, wk, wT0, wpk);

    dim3 cgrid(96, 96, 2);
    k_conv0<<<cgrid, 192, 0, stream>>>(data, wT0, buf0, spart);
    k_finalize<<<64, 256, 0, stream>>>((const float2*)spart, mr + 0);

    k_convk_v3<0><<<2304, 512, 0, stream>>>(buf0, mr + 0,   wpk + 0 * 27648, buf1, spart);
    k_finalize<<<64, 256, 0, stream>>>((const float2*)spart, mr + 64);

    k_convk_v3<0><<<2304, 512, 0, stream>>>(buf1, mr + 64,  wpk + 1 * 27648, buf0, spart);
    k_finalize<<<64, 256, 0, stream>>>((const float2*)spart, mr + 128);

    k_convk_v3<1><<<2304, 512, 0, stream>>>(buf0, mr + 128, wpk + 2 * 27648, buf1, spart);
    k_finalize<<<64, 256, 0, stream>>>((const float2*)spart, mr + 192);

    k_pool_mfma<<<432, 448, 0, stream>>>(buf1, mask, mr + 192, rzone, mzone);
    k_roifin<<<100, 256, 0, stream>>>(rzone, mzone, roi);

    k_mlp<<<dim3(100, 2), 256, 0, stream>>>(roi, sw1, sb1, sw2, sb2,
                                            pw1, pb1, pw2, pb2, out);
}